// Round 1
// baseline (1056.949 us; speedup 1.0000x reference)
//
#include <hip/hip_runtime.h>
#include <cstdint>
#include <cstddef>

#define NB 16
#define TT 12
#define NN 1024
#define DD 64
#define FF 64
#define JT 768   // T*D

__device__ __forceinline__ float sigmoidf_(float v) { return 1.0f / (1.0f + expf(-v)); }

// ---------------- propagation GEMM: Xout[b] = A[b] @ Xin[b] ----------------
// A: (B, N, N) row-major. Xout: (B, N, 768). Xin: either x (B,T,N,D) [XFROMX]
// with col j -> (t=j/64, d=j%64), or materialized (B, N, 768).
template<bool XFROMX>
__global__ __launch_bounds__(256) void gemm_prop(
    const float* __restrict__ A, const float* __restrict__ Xin,
    float* __restrict__ Xout)
{
    __shared__ float As[32][132];   // transposed: As[k][w]
    __shared__ float Bs[32][132];   // Bs[k][j]
    const int cb = blockIdx.x;      // 0..5 col block (128 cols)
    const int rb = blockIdx.y;      // 0..7 row block (128 rows)
    const int b  = blockIdx.z;      // 0..15
    const int tid = threadIdx.x;
    const int w0 = rb * 128, j0 = cb * 128;
    const float* Ab = A + (size_t)b * NN * NN;
    const int rg = tid >> 4, cg = tid & 15;
    const int row0 = rg * 8;

    float acc[8][8];
#pragma unroll
    for (int i = 0; i < 8; ++i)
#pragma unroll
        for (int j = 0; j < 8; ++j) acc[i][j] = 0.0f;

    for (int kt = 0; kt < NN / 32; ++kt) {
        __syncthreads();
        // A tile: 128 rows x 32 k, transpose into As[k][w]
#pragma unroll
        for (int p = 0; p < 4; ++p) {
            const int row = (tid >> 3) + p * 32;
            const int k4  = (tid & 7) * 4;
            const float4 v = *(const float4*)&Ab[(size_t)(w0 + row) * NN + kt * 32 + k4];
            As[k4 + 0][row] = v.x; As[k4 + 1][row] = v.y;
            As[k4 + 2][row] = v.z; As[k4 + 3][row] = v.w;
        }
        // B tile: 32 k x 128 j
#pragma unroll
        for (int p = 0; p < 4; ++p) {
            const int kr = (tid >> 5) + p * 8;
            const int j  = (tid & 31) * 4;
            float4 v;
            if (XFROMX) {
                const int t = cb * 2 + (j >> 6);
                const int d = j & 63;
                v = *(const float4*)&Xin[(((size_t)b * TT + t) * NN + kt * 32 + kr) * DD + d];
            } else {
                v = *(const float4*)&Xin[((size_t)b * NN + kt * 32 + kr) * JT + j0 + j];
            }
            *(float4*)&Bs[kr][j] = v;
        }
        __syncthreads();
#pragma unroll
        for (int k = 0; k < 32; ++k) {
            float a[8], bb[8];
            *(float4*)&a[0]  = *(const float4*)&As[k][row0];
            *(float4*)&a[4]  = *(const float4*)&As[k][row0 + 4];
            *(float4*)&bb[0] = *(const float4*)&Bs[k][cg * 4];
            *(float4*)&bb[4] = *(const float4*)&Bs[k][64 + cg * 4];
#pragma unroll
            for (int i = 0; i < 8; ++i)
#pragma unroll
                for (int j = 0; j < 8; ++j)
                    acc[i][j] = fmaf(a[i], bb[j], acc[i][j]);
        }
    }
#pragma unroll
    for (int i = 0; i < 8; ++i) {
        float4 v0 = {acc[i][0], acc[i][1], acc[i][2], acc[i][3]};
        float4 v1 = {acc[i][4], acc[i][5], acc[i][6], acc[i][7]};
        float* dst = Xout + ((size_t)b * NN + w0 + row0 + i) * JT + j0;
        *(float4*)&dst[cg * 4]      = v0;
        *(float4*)&dst[64 + cg * 4] = v1;
    }
}

// ---------------- conv (BTN x 192 @ 192 x 64) + BN + ReLU ----------------
__global__ __launch_bounds__(256) void conv_bn_relu(
    const float* __restrict__ x,  const float* __restrict__ X1,
    const float* __restrict__ X2, const float* __restrict__ W,
    const float* __restrict__ convb, const float* __restrict__ gamma,
    const float* __restrict__ beta,  const float* __restrict__ mean,
    const float* __restrict__ var,   float* __restrict__ y)
{
    __shared__ float As[64][132];   // As[c][row]
    __shared__ float Ws[64][68];    // Ws[c][f]
    const int nb = blockIdx.x, t = blockIdx.y, b = blockIdx.z;
    const int n0 = nb * 128;
    const int tid = threadIdx.x;
    const int rg = tid >> 4, cg = tid & 15;
    const int row0 = rg * 8, f0 = cg * 4;

    float acc[8][4];
#pragma unroll
    for (int i = 0; i < 8; ++i)
#pragma unroll
        for (int j = 0; j < 4; ++j) acc[i][j] = 0.0f;

    for (int kt = 0; kt < 3; ++kt) {
        const float* src;
        size_t rstride;
        if (kt == 0) { src = x + (((size_t)b * TT + t) * NN + n0) * DD; rstride = DD; }
        else {
            const float* Xk = (kt == 1) ? X1 : X2;
            src = Xk + ((size_t)b * NN + n0) * JT + t * DD; rstride = JT;
        }
        __syncthreads();
        // input tile 128 rows x 64 c, transposed
#pragma unroll
        for (int p = 0; p < 8; ++p) {
            const int row = (tid >> 4) + p * 16;
            const int c4  = (tid & 15) * 4;
            const float4 v = *(const float4*)&src[(size_t)row * rstride + c4];
            As[c4 + 0][row] = v.x; As[c4 + 1][row] = v.y;
            As[c4 + 2][row] = v.z; As[c4 + 3][row] = v.w;
        }
        // weight tile 64 f x 64 c -> Ws[c][f]
#pragma unroll
        for (int p = 0; p < 4; ++p) {
            const int f  = (tid >> 4) + p * 16;
            const int c4 = (tid & 15) * 4;
            const float4 v = *(const float4*)&W[f * 192 + kt * 64 + c4];
            Ws[c4 + 0][f] = v.x; Ws[c4 + 1][f] = v.y;
            Ws[c4 + 2][f] = v.z; Ws[c4 + 3][f] = v.w;
        }
        __syncthreads();
#pragma unroll
        for (int k = 0; k < 64; ++k) {
            float a[8], w[4];
            *(float4*)&a[0] = *(const float4*)&As[k][row0];
            *(float4*)&a[4] = *(const float4*)&As[k][row0 + 4];
            *(float4*)&w[0] = *(const float4*)&Ws[k][f0];
#pragma unroll
            for (int i = 0; i < 8; ++i)
#pragma unroll
                for (int j = 0; j < 4; ++j)
                    acc[i][j] = fmaf(a[i], w[j], acc[i][j]);
        }
    }
    // epilogue: BN + ReLU. y = relu(acc * s + off)
    float s[4], off[4];
#pragma unroll
    for (int j = 0; j < 4; ++j) {
        const int f = f0 + j;
        const float sc = gamma[f] / sqrtf(var[f] + 1e-5f);
        s[j]   = sc;
        off[j] = (convb[f] - mean[f]) * sc + beta[f];
    }
#pragma unroll
    for (int i = 0; i < 8; ++i) {
        float4 v;
        v.x = fmaxf(acc[i][0] * s[0] + off[0], 0.0f);
        v.y = fmaxf(acc[i][1] * s[1] + off[1], 0.0f);
        v.z = fmaxf(acc[i][2] * s[2] + off[2], 0.0f);
        v.w = fmaxf(acc[i][3] * s[3] + off[3], 0.0f);
        *(float4*)&y[(((size_t)b * TT + t) * NN + n0 + row0 + i) * FF + f0] = v;
    }
}

// ---------------- fused GRU step t ----------------
// Per block: 64 rows m (same b). ru = sigmoid([x_t,h] @ Wff + bff);
// r*h overwrites LDS h-half; z = tanh([x_t,r*h] @ Wzff + bzff);
// hnew = u*z + (1-u)*h ; write h and d_out[b][t][n][f].
__global__ __launch_bounds__(256) void gru_step(
    const float* __restrict__ y,    const float* __restrict__ wff,
    const float* __restrict__ bff,  const float* __restrict__ wzff,
    const float* __restrict__ bzff, float* __restrict__ h,
    float* __restrict__ out, const int t)
{
    __shared__ float As[128][68];   // As[k][m]: k<64 x_t, k>=64 h (then r*h)
    __shared__ float Ws[32][132];   // weight K-tile
    const int m0 = blockIdx.x * 64;
    const int b  = m0 >> 10, n0 = m0 & 1023;
    const int tid = threadIdx.x;
    const int rg = tid >> 4, og = tid & 15;

    const float* xt = y + (((size_t)b * TT + t) * NN + n0) * DD;
    float* hb = h + ((size_t)b * NN + n0) * DD;

    // stage inputs (transposed)
#pragma unroll
    for (int p = 0; p < 4; ++p) {
        const int r  = (tid >> 4) + p * 16;
        const int c4 = (tid & 15) * 4;
        const float4 v = *(const float4*)&xt[r * DD + c4];
        As[c4 + 0][r] = v.x; As[c4 + 1][r] = v.y;
        As[c4 + 2][r] = v.z; As[c4 + 3][r] = v.w;
        float4 hv = make_float4(0.f, 0.f, 0.f, 0.f);
        if (t > 0) hv = *(const float4*)&hb[r * DD + c4];
        As[64 + c4 + 0][r] = hv.x; As[64 + c4 + 1][r] = hv.y;
        As[64 + c4 + 2][r] = hv.z; As[64 + c4 + 3][r] = hv.w;
    }

    // ---- ru GEMM: 64 rows x 128 outs; thread: rows rg*4+(0..3),
    //      outs og*4+(0..3) [r-part] and 64+og*4+(0..3) [u-part]
    float acc[4][8];
#pragma unroll
    for (int i = 0; i < 4; ++i)
#pragma unroll
        for (int j = 0; j < 8; ++j) acc[i][j] = 0.0f;

    for (int kt = 0; kt < 4; ++kt) {
        __syncthreads();   // staging done (kt=0) / prev reads of Ws done (kt>0)
#pragma unroll
        for (int p = 0; p < 4; ++p) {
            const int kk = (tid >> 5) + p * 8;
            const int o4 = (tid & 31) * 4;
            *(float4*)&Ws[kk][o4] =
                *(const float4*)&wff[((size_t)t * 128 + kt * 32 + kk) * 128 + o4];
        }
        __syncthreads();
#pragma unroll
        for (int kk = 0; kk < 32; ++kk) {
            float a[4], w[8];
            *(float4*)&a[0] = *(const float4*)&As[kt * 32 + kk][rg * 4];
            *(float4*)&w[0] = *(const float4*)&Ws[kk][og * 4];
            *(float4*)&w[4] = *(const float4*)&Ws[kk][64 + og * 4];
#pragma unroll
            for (int i = 0; i < 4; ++i)
#pragma unroll
                for (int j = 0; j < 8; ++j)
                    acc[i][j] = fmaf(a[i], w[j], acc[i][j]);
        }
    }
    __syncthreads();   // all As/Ws reads of ru phase complete

    float4 b0 = *(const float4*)&bff[(size_t)t * 128 + og * 4];
    float4 b1 = *(const float4*)&bff[(size_t)t * 128 + 64 + og * 4];
    float rv[4][4], uv[4][4];
#pragma unroll
    for (int i = 0; i < 4; ++i) {
        rv[i][0] = sigmoidf_(acc[i][0] + b0.x);
        rv[i][1] = sigmoidf_(acc[i][1] + b0.y);
        rv[i][2] = sigmoidf_(acc[i][2] + b0.z);
        rv[i][3] = sigmoidf_(acc[i][3] + b0.w);
        uv[i][0] = sigmoidf_(acc[i][4] + b1.x);
        uv[i][1] = sigmoidf_(acc[i][5] + b1.y);
        uv[i][2] = sigmoidf_(acc[i][6] + b1.z);
        uv[i][3] = sigmoidf_(acc[i][7] + b1.w);
    }
    // r*h overwrites h-half of As (each (o,m) owned by exactly one thread)
#pragma unroll
    for (int i = 0; i < 4; ++i)
#pragma unroll
        for (int j = 0; j < 4; ++j) {
            const int o = og * 4 + j, m = rg * 4 + i;
            As[64 + o][m] = rv[i][j] * As[64 + o][m];
        }
    __syncthreads();

    // ---- z GEMM: 64 rows x 64 outs; thread: rows rg*4+(0..3), f og*4+(0..3)
    float accz[4][4];
#pragma unroll
    for (int i = 0; i < 4; ++i)
#pragma unroll
        for (int j = 0; j < 4; ++j) accz[i][j] = 0.0f;

    for (int kt = 0; kt < 4; ++kt) {
#pragma unroll
        for (int p = 0; p < 2; ++p) {
            const int kk = (tid >> 4) + p * 16;
            const int f4 = (tid & 15) * 4;
            *(float4*)&Ws[kk][f4] =
                *(const float4*)&wzff[((size_t)t * 128 + kt * 32 + kk) * 64 + f4];
        }
        __syncthreads();
#pragma unroll
        for (int kk = 0; kk < 32; ++kk) {
            float a[4], w[4];
            *(float4*)&a[0] = *(const float4*)&As[kt * 32 + kk][rg * 4];
            *(float4*)&w[0] = *(const float4*)&Ws[kk][og * 4];
#pragma unroll
            for (int i = 0; i < 4; ++i)
#pragma unroll
                for (int j = 0; j < 4; ++j)
                    accz[i][j] = fmaf(a[i], w[j], accz[i][j]);
        }
        __syncthreads();   // protect Ws before next tile's load
    }

    // epilogue: hnew = u*z + (1-u)*h_old ; store to h and out
    float4 bz = *(const float4*)&bzff[(size_t)t * 64 + og * 4];
#pragma unroll
    for (int i = 0; i < 4; ++i) {
        const int m = rg * 4 + i;
        float4 hold = make_float4(0.f, 0.f, 0.f, 0.f);
        if (t > 0) hold = *(const float4*)&hb[m * DD + og * 4];
        const float z0 = tanhf(accz[i][0] + bz.x);
        const float z1 = tanhf(accz[i][1] + bz.y);
        const float z2 = tanhf(accz[i][2] + bz.z);
        const float z3 = tanhf(accz[i][3] + bz.w);
        float4 hv;
        hv.x = uv[i][0] * z0 + (1.0f - uv[i][0]) * hold.x;
        hv.y = uv[i][1] * z1 + (1.0f - uv[i][1]) * hold.y;
        hv.z = uv[i][2] * z2 + (1.0f - uv[i][2]) * hold.z;
        hv.w = uv[i][3] * z3 + (1.0f - uv[i][3]) * hold.w;
        *(float4*)&hb[m * DD + og * 4] = hv;
        *(float4*)&out[(((size_t)b * TT + t) * NN + n0 + m) * FF + og * 4] = hv;
    }
}

extern "C" void kernel_launch(void* const* d_in, const int* in_sizes, int n_in,
                              void* d_out, int out_size, void* d_ws, size_t ws_size,
                              hipStream_t stream)
{
    const float* x        = (const float*)d_in[0];
    const float* A        = (const float*)d_in[1];
    const float* conv_w   = (const float*)d_in[2];
    const float* conv_b   = (const float*)d_in[3];
    const float* bn_gamma = (const float*)d_in[4];
    const float* bn_beta  = (const float*)d_in[5];
    const float* bn_mean  = (const float*)d_in[6];
    const float* bn_var   = (const float*)d_in[7];
    const float* gru_ff_w = (const float*)d_in[8];
    const float* gru_ff_b = (const float*)d_in[9];
    const float* gru_zff_w = (const float*)d_in[10];
    const float* gru_zff_b = (const float*)d_in[11];
    float* out = (float*)d_out;
    float* ws  = (float*)d_ws;

    const size_t szX = (size_t)NB * NN * JT;   // 12,582,912 floats
    float* X1 = ws;
    float* X2 = ws + szX;
    float* yb = ws + 2 * szX;
    float* hb = ws + 3 * szX;                   // (B,N,F)

    dim3 gprop(6, 8, NB);
    gemm_prop<true ><<<gprop, 256, 0, stream>>>(A, x,  X1);
    gemm_prop<false><<<gprop, 256, 0, stream>>>(A, X1, X2);

    dim3 gconv(8, TT, NB);
    conv_bn_relu<<<gconv, 256, 0, stream>>>(x, X1, X2, conv_w, conv_b,
                                            bn_gamma, bn_beta, bn_mean, bn_var, yb);

    for (int t = 0; t < TT; ++t)
        gru_step<<<dim3(256), 256, 0, stream>>>(yb, gru_ff_w, gru_ff_b,
                                                gru_zff_w, gru_zff_b, hb, out, t);
}

// Round 2
// 995.245 us; speedup vs baseline: 1.0620x; 1.0620x over previous
//
#include <hip/hip_runtime.h>
#include <cstdint>
#include <cstddef>

#define NB 16
#define TT 12
#define NN 1024
#define DD 64
#define FF 64
#define JT 768   // T*D

__device__ __forceinline__ float sigmoidf_(float v) { return 1.0f / (1.0f + expf(-v)); }

__device__ __forceinline__ void gload16(const float* g, float* lds) {
    __builtin_amdgcn_global_load_lds(
        (const __attribute__((address_space(1))) void*)g,
        (__attribute__((address_space(3))) void*)lds, 16, 0, 0);
}

// ---------------- A transpose: At[b][v][w] = A[b][w][v] ----------------
__global__ __launch_bounds__(256) void transpose_A(
    const float* __restrict__ A, float* __restrict__ At)
{
    __shared__ float tile[64][65];
    const int b = blockIdx.z;
    const int w0 = blockIdx.x * 64;   // A row tile
    const int v0 = blockIdx.y * 64;   // A col tile
    const int tid = threadIdx.x;
    const int r  = tid >> 2;          // 0..63
    const int c0 = (tid & 3) * 16;
    const float* Ab = A + (size_t)b * NN * NN;
    float* Atb = At + (size_t)b * NN * NN;
#pragma unroll
    for (int p = 0; p < 4; ++p) {
        const float4 v = *(const float4*)&Ab[(size_t)(w0 + r) * NN + v0 + c0 + p * 4];
        tile[r][c0 + p * 4 + 0] = v.x; tile[r][c0 + p * 4 + 1] = v.y;
        tile[r][c0 + p * 4 + 2] = v.z; tile[r][c0 + p * 4 + 3] = v.w;
    }
    __syncthreads();
#pragma unroll
    for (int p = 0; p < 4; ++p) {
        float4 v;
        v.x = tile[c0 + p * 4 + 0][r]; v.y = tile[c0 + p * 4 + 1][r];
        v.z = tile[c0 + p * 4 + 2][r]; v.w = tile[c0 + p * 4 + 3][r];
        *(float4*)&Atb[(size_t)(v0 + r) * NN + w0 + c0 + p * 4] = v;
    }
}

// ---------------- propagation GEMM: Xout[b] = A[b] @ Xin[b] ----------------
// ATRANS: Aop = At (k-major), staged via global_load_lds, linear [32][128].
// else:   Aop = A, reg-transpose staging with pad 132 (fallback if ws small).
// XFROMX: Xin = x (B,T,N,D), col j -> (t=j/64, d=j%64); else (B,N,768).
template<bool XFROMX, bool ATRANS>
__global__ __launch_bounds__(256) void gemm_prop(
    const float* __restrict__ Aop, const float* __restrict__ Xin,
    float* __restrict__ Xout)
{
    constexpr int AST = ATRANS ? 128 : 132;
    __shared__ float As[2][32 * AST];
    __shared__ float Bs[2][32 * 128];

    // bijective XCD swizzle: 768 blocks, 96 per XCD -> each XCD owns 2 batches
    const int wg  = blockIdx.x;
    const int nlin = (wg & 7) * 96 + (wg >> 3);
    const int b  = nlin / 48;
    const int rr = nlin % 48;
    const int rb = rr / 6, cb = rr % 6;
    const int w0 = rb * 128, j0 = cb * 128;

    const int tid = threadIdx.x, lane = tid & 63, wid = tid >> 6;
    const int rg = tid >> 4, cg = tid & 15;
    const int row0 = rg * 8;

    auto stage = [&](int buf, int kt) {
        if constexpr (ATRANS) {
            const float* abase = Aop + ((size_t)b * NN + (size_t)kt * 32) * NN + w0;
#pragma unroll
            for (int p = 0; p < 4; ++p) {
                const int chunk = wid * 4 + p;
                const int k = 2 * chunk + (lane >> 5);
                gload16(abase + (size_t)k * NN + (lane & 31) * 4, &As[buf][chunk * 256]);
            }
        } else {
            const float* Ab = Aop + (size_t)b * NN * NN;
#pragma unroll
            for (int p = 0; p < 4; ++p) {
                const int w  = (tid >> 3) + p * 32;
                const int k4 = (tid & 7) * 4;
                const float4 v = *(const float4*)&Ab[(size_t)(w0 + w) * NN + kt * 32 + k4];
                As[buf][(k4 + 0) * 132 + w] = v.x;
                As[buf][(k4 + 1) * 132 + w] = v.y;
                As[buf][(k4 + 2) * 132 + w] = v.z;
                As[buf][(k4 + 3) * 132 + w] = v.w;
            }
        }
#pragma unroll
        for (int p = 0; p < 4; ++p) {
            const int chunk = wid * 4 + p;
            const int k = 2 * chunk + (lane >> 5);
            const float* g;
            if constexpr (XFROMX) {
                const int jj = (lane & 31) * 4;
                const int t = cb * 2 + (jj >> 6);
                const int d = jj & 63;
                g = Xin + (((size_t)b * TT + t) * NN + (size_t)kt * 32 + k) * DD + d;
            } else {
                g = Xin + ((size_t)b * NN + (size_t)kt * 32 + k) * JT + j0 + (lane & 31) * 4;
            }
            gload16(g, &Bs[buf][chunk * 256]);
        }
    };

    float acc[8][8];
#pragma unroll
    for (int i = 0; i < 8; ++i)
#pragma unroll
        for (int j = 0; j < 8; ++j) acc[i][j] = 0.0f;

    stage(0, 0);
    __syncthreads();            // drains tile-0 loads
    int cur = 0;
    for (int kt = 0; kt < 32; ++kt) {
        if (kt + 1 < 32) stage(cur ^ 1, kt + 1);   // issue next-tile loads (overlap)
#pragma unroll
        for (int k = 0; k < 32; ++k) {
            float a[8], bb[8];
            *(float4*)&a[0]  = *(const float4*)&As[cur][k * AST + row0];
            *(float4*)&a[4]  = *(const float4*)&As[cur][k * AST + row0 + 4];
            *(float4*)&bb[0] = *(const float4*)&Bs[cur][k * 128 + cg * 4];
            *(float4*)&bb[4] = *(const float4*)&Bs[cur][k * 128 + 64 + cg * 4];
#pragma unroll
            for (int i = 0; i < 8; ++i)
#pragma unroll
                for (int j = 0; j < 8; ++j)
                    acc[i][j] = fmaf(a[i], bb[j], acc[i][j]);
        }
        __syncthreads();        // drains next-tile loads + fences cur reads
        cur ^= 1;
    }
#pragma unroll
    for (int i = 0; i < 8; ++i) {
        float4 v0 = {acc[i][0], acc[i][1], acc[i][2], acc[i][3]};
        float4 v1 = {acc[i][4], acc[i][5], acc[i][6], acc[i][7]};
        float* dst = Xout + ((size_t)b * NN + w0 + row0 + i) * JT + j0;
        *(float4*)&dst[cg * 4]      = v0;
        *(float4*)&dst[64 + cg * 4] = v1;
    }
}

// ---------------- conv (BTN x 192 @ 192 x 64) + BN + ReLU ----------------
__global__ __launch_bounds__(256) void conv_bn_relu(
    const float* __restrict__ x,  const float* __restrict__ X1,
    const float* __restrict__ X2, const float* __restrict__ W,
    const float* __restrict__ convb, const float* __restrict__ gamma,
    const float* __restrict__ beta,  const float* __restrict__ mean,
    const float* __restrict__ var,   float* __restrict__ y)
{
    __shared__ float As[64][132];
    __shared__ float Ws[64][68];
    const int nb = blockIdx.x, t = blockIdx.y, b = blockIdx.z;
    const int n0 = nb * 128;
    const int tid = threadIdx.x;
    const int rg = tid >> 4, cg = tid & 15;
    const int row0 = rg * 8, f0 = cg * 4;

    float acc[8][4];
#pragma unroll
    for (int i = 0; i < 8; ++i)
#pragma unroll
        for (int j = 0; j < 4; ++j) acc[i][j] = 0.0f;

    for (int kt = 0; kt < 3; ++kt) {
        const float* src;
        size_t rstride;
        if (kt == 0) { src = x + (((size_t)b * TT + t) * NN + n0) * DD; rstride = DD; }
        else {
            const float* Xk = (kt == 1) ? X1 : X2;
            src = Xk + ((size_t)b * NN + n0) * JT + t * DD; rstride = JT;
        }
        __syncthreads();
#pragma unroll
        for (int p = 0; p < 8; ++p) {
            const int row = (tid >> 4) + p * 16;
            const int c4  = (tid & 15) * 4;
            const float4 v = *(const float4*)&src[(size_t)row * rstride + c4];
            As[c4 + 0][row] = v.x; As[c4 + 1][row] = v.y;
            As[c4 + 2][row] = v.z; As[c4 + 3][row] = v.w;
        }
#pragma unroll
        for (int p = 0; p < 4; ++p) {
            const int f  = (tid >> 4) + p * 16;
            const int c4 = (tid & 15) * 4;
            const float4 v = *(const float4*)&W[f * 192 + kt * 64 + c4];
            Ws[c4 + 0][f] = v.x; Ws[c4 + 1][f] = v.y;
            Ws[c4 + 2][f] = v.z; Ws[c4 + 3][f] = v.w;
        }
        __syncthreads();
#pragma unroll
        for (int k = 0; k < 64; ++k) {
            float a[8], w[4];
            *(float4*)&a[0] = *(const float4*)&As[k][row0];
            *(float4*)&a[4] = *(const float4*)&As[k][row0 + 4];
            *(float4*)&w[0] = *(const float4*)&Ws[k][f0];
#pragma unroll
            for (int i = 0; i < 8; ++i)
#pragma unroll
                for (int j = 0; j < 4; ++j)
                    acc[i][j] = fmaf(a[i], w[j], acc[i][j]);
        }
    }
    float s[4], off[4];
#pragma unroll
    for (int j = 0; j < 4; ++j) {
        const int f = f0 + j;
        const float sc = gamma[f] / sqrtf(var[f] + 1e-5f);
        s[j]   = sc;
        off[j] = (convb[f] - mean[f]) * sc + beta[f];
    }
#pragma unroll
    for (int i = 0; i < 8; ++i) {
        float4 v;
        v.x = fmaxf(acc[i][0] * s[0] + off[0], 0.0f);
        v.y = fmaxf(acc[i][1] * s[1] + off[1], 0.0f);
        v.z = fmaxf(acc[i][2] * s[2] + off[2], 0.0f);
        v.w = fmaxf(acc[i][3] * s[3] + off[3], 0.0f);
        *(float4*)&y[(((size_t)b * TT + t) * NN + n0 + row0 + i) * FF + f0] = v;
    }
}

// ---------------- fused GRU, all 12 steps in one kernel ----------------
// 512 blocks x 32 rows; h state lives in LDS across steps (rows independent).
__global__ __launch_bounds__(256) void gru_all(
    const float* __restrict__ y,    const float* __restrict__ wff,
    const float* __restrict__ bff,  const float* __restrict__ wzff,
    const float* __restrict__ bzff, float* __restrict__ out)
{
    __shared__ float Xs[64][36];   // xt transposed [c][m]
    __shared__ float Hs[64][36];   // h state [f][m], persists across t
    __shared__ float Rs[64][36];   // r*h [f][m]
    __shared__ float Us[64][36];   // u [f][m]
    __shared__ float Ws[64][132];  // weight K-tile (BK=64)
    const int tid = threadIdx.x;
    const int mb  = blockIdx.x;
    const int b = mb >> 5, n0 = (mb & 31) * 32;
    const int rg = tid >> 5;       // rows rg*4 .. +3
    const int og = tid & 31;       // ru outs og*4..; z outs og*2..

    for (int i = tid; i < 64 * 36; i += 256) (&Hs[0][0])[i] = 0.0f;

    for (int t = 0; t < TT; ++t) {
        {   // stage Xs (transposed)
            const float* xt = y + (((size_t)b * TT + t) * NN + n0) * DD;
            const int m = tid >> 3, c0 = (tid & 7) * 8;
            const float4 v0 = *(const float4*)&xt[m * DD + c0];
            const float4 v1 = *(const float4*)&xt[m * DD + c0 + 4];
            Xs[c0 + 0][m] = v0.x; Xs[c0 + 1][m] = v0.y;
            Xs[c0 + 2][m] = v0.z; Xs[c0 + 3][m] = v0.w;
            Xs[c0 + 4][m] = v1.x; Xs[c0 + 5][m] = v1.y;
            Xs[c0 + 6][m] = v1.z; Xs[c0 + 7][m] = v1.w;
        }
        // ---- ru GEMM: 32 rows x 128 outs, K=128 ([Xs; Hs])
        float acc[4][4];
#pragma unroll
        for (int i = 0; i < 4; ++i)
#pragma unroll
            for (int j = 0; j < 4; ++j) acc[i][j] = 0.0f;

#pragma unroll
        for (int half = 0; half < 2; ++half) {
            __syncthreads();   // fences Xs staging / Hs init / prev Ws reads
#pragma unroll
            for (int p = 0; p < 8; ++p) {
                const int kk = (tid >> 5) + p * 8;
                const int o4 = (tid & 31) * 4;
                *(float4*)&Ws[kk][o4] =
                    *(const float4*)&wff[((size_t)t * 128 + half * 64 + kk) * 128 + o4];
            }
            __syncthreads();
            const float (*Asrc)[36] = half ? Hs : Xs;
#pragma unroll 4
            for (int kk = 0; kk < 64; ++kk) {
                const float4 av = *(const float4*)&Asrc[kk][rg * 4];
                const float4 wv = *(const float4*)&Ws[kk][og * 4];
                const float a0 = av.x, a1 = av.y, a2 = av.z, a3 = av.w;
                acc[0][0] = fmaf(a0, wv.x, acc[0][0]); acc[0][1] = fmaf(a0, wv.y, acc[0][1]);
                acc[0][2] = fmaf(a0, wv.z, acc[0][2]); acc[0][3] = fmaf(a0, wv.w, acc[0][3]);
                acc[1][0] = fmaf(a1, wv.x, acc[1][0]); acc[1][1] = fmaf(a1, wv.y, acc[1][1]);
                acc[1][2] = fmaf(a1, wv.z, acc[1][2]); acc[1][3] = fmaf(a1, wv.w, acc[1][3]);
                acc[2][0] = fmaf(a2, wv.x, acc[2][0]); acc[2][1] = fmaf(a2, wv.y, acc[2][1]);
                acc[2][2] = fmaf(a2, wv.z, acc[2][2]); acc[2][3] = fmaf(a2, wv.w, acc[2][3]);
                acc[3][0] = fmaf(a3, wv.x, acc[3][0]); acc[3][1] = fmaf(a3, wv.y, acc[3][1]);
                acc[3][2] = fmaf(a3, wv.z, acc[3][2]); acc[3][3] = fmaf(a3, wv.w, acc[3][3]);
            }
        }
        // ---- activations; r-threads write Rs = r*h, u-threads write Us
        {
            const float4 bb4 = *(const float4*)&bff[(size_t)t * 128 + og * 4];
            float g[4][4];
#pragma unroll
            for (int i = 0; i < 4; ++i) {
                g[i][0] = sigmoidf_(acc[i][0] + bb4.x);
                g[i][1] = sigmoidf_(acc[i][1] + bb4.y);
                g[i][2] = sigmoidf_(acc[i][2] + bb4.z);
                g[i][3] = sigmoidf_(acc[i][3] + bb4.w);
            }
            if (og < 16) {
#pragma unroll
                for (int i = 0; i < 4; ++i)
#pragma unroll
                    for (int j = 0; j < 4; ++j) {
                        const int f = og * 4 + j, m = rg * 4 + i;
                        Rs[f][m] = g[i][j] * Hs[f][m];
                    }
            } else {
#pragma unroll
                for (int i = 0; i < 4; ++i)
#pragma unroll
                    for (int j = 0; j < 4; ++j)
                        Us[og * 4 + j - 64][rg * 4 + i] = g[i][j];
            }
        }
        // ---- z GEMM: 32 rows x 64 outs, K=128 ([Xs; Rs])
        float accz[4][2];
#pragma unroll
        for (int i = 0; i < 4; ++i) { accz[i][0] = 0.0f; accz[i][1] = 0.0f; }

#pragma unroll
        for (int half = 0; half < 2; ++half) {
            __syncthreads();   // fences Rs/Us writes and prior Ws reads
#pragma unroll
            for (int p = 0; p < 4; ++p) {
                const int kk = (tid >> 4) + p * 16;
                const int f4 = (tid & 15) * 4;
                *(float4*)&Ws[kk][f4] =
                    *(const float4*)&wzff[((size_t)t * 128 + half * 64 + kk) * 64 + f4];
            }
            __syncthreads();
            const float (*Asrc)[36] = half ? Rs : Xs;
#pragma unroll 4
            for (int kk = 0; kk < 64; ++kk) {
                const float4 av = *(const float4*)&Asrc[kk][rg * 4];
                const float2 wv = *(const float2*)&Ws[kk][og * 2];
                accz[0][0] = fmaf(av.x, wv.x, accz[0][0]); accz[0][1] = fmaf(av.x, wv.y, accz[0][1]);
                accz[1][0] = fmaf(av.y, wv.x, accz[1][0]); accz[1][1] = fmaf(av.y, wv.y, accz[1][1]);
                accz[2][0] = fmaf(av.z, wv.x, accz[2][0]); accz[2][1] = fmaf(av.z, wv.y, accz[2][1]);
                accz[3][0] = fmaf(av.w, wv.x, accz[3][0]); accz[3][1] = fmaf(av.w, wv.y, accz[3][1]);
            }
        }
        // ---- epilogue: hnew = u*z + (1-u)*h_old  (each (f,m) owner-exclusive)
        {
            const float2 bz = *(const float2*)&bzff[(size_t)t * 64 + og * 2];
            const int f0_ = og * 2;
#pragma unroll
            for (int i = 0; i < 4; ++i) {
                const int m = rg * 4 + i;
                const float z0 = tanhf(accz[i][0] + bz.x);
                const float z1 = tanhf(accz[i][1] + bz.y);
                const float u0 = Us[f0_][m],     u1 = Us[f0_ + 1][m];
                const float h0 = Hs[f0_][m],     h1 = Hs[f0_ + 1][m];
                const float hn0 = u0 * z0 + (1.0f - u0) * h0;
                const float hn1 = u1 * z1 + (1.0f - u1) * h1;
                Hs[f0_][m] = hn0; Hs[f0_ + 1][m] = hn1;
                *(float2*)&out[(((size_t)b * TT + t) * NN + n0 + m) * FF + f0_] =
                    make_float2(hn0, hn1);
            }
        }
        __syncthreads();   // h updates visible; Xs/Rs/Us/Ws reusable next t
    }
}

extern "C" void kernel_launch(void* const* d_in, const int* in_sizes, int n_in,
                              void* d_out, int out_size, void* d_ws, size_t ws_size,
                              hipStream_t stream)
{
    const float* x        = (const float*)d_in[0];
    const float* A        = (const float*)d_in[1];
    const float* conv_w   = (const float*)d_in[2];
    const float* conv_b   = (const float*)d_in[3];
    const float* bn_gamma = (const float*)d_in[4];
    const float* bn_beta  = (const float*)d_in[5];
    const float* bn_mean  = (const float*)d_in[6];
    const float* bn_var   = (const float*)d_in[7];
    const float* gru_ff_w  = (const float*)d_in[8];
    const float* gru_ff_b  = (const float*)d_in[9];
    const float* gru_zff_w = (const float*)d_in[10];
    const float* gru_zff_b = (const float*)d_in[11];
    float* out = (float*)d_out;
    float* ws  = (float*)d_ws;

    const size_t szX = (size_t)NB * NN * JT;     // 12.58M floats
    const size_t szA = (size_t)NB * NN * NN;     // 16.78M floats
    float* X1 = ws;
    float* X2 = ws + szX;

    const bool useAt = ws_size >= (2 * szX + szA) * sizeof(float);
    dim3 gconv(8, TT, NB);

    if (useAt) {
        float* At = ws + 2 * szX;
        float* yb = At;                 // y aliases At: At is dead after gemm2
        transpose_A<<<dim3(16, 16, NB), 256, 0, stream>>>(A, At);
        gemm_prop<true,  true><<<768, 256, 0, stream>>>(At, x,  X1);
        gemm_prop<false, true><<<768, 256, 0, stream>>>(At, X1, X2);
        conv_bn_relu<<<gconv, 256, 0, stream>>>(x, X1, X2, conv_w, conv_b,
                                                bn_gamma, bn_beta, bn_mean, bn_var, yb);
        gru_all<<<512, 256, 0, stream>>>(yb, gru_ff_w, gru_ff_b,
                                         gru_zff_w, gru_zff_b, out);
    } else {
        float* yb = ws + 2 * szX;
        gemm_prop<true,  false><<<768, 256, 0, stream>>>(A, x,  X1);
        gemm_prop<false, false><<<768, 256, 0, stream>>>(A, X1, X2);
        conv_bn_relu<<<gconv, 256, 0, stream>>>(x, X1, X2, conv_w, conv_b,
                                                bn_gamma, bn_beta, bn_mean, bn_var, yb);
        gru_all<<<512, 256, 0, stream>>>(yb, gru_ff_w, gru_ff_b,
                                         gru_zff_w, gru_zff_b, out);
    }
}

// Round 3
// 891.313 us; speedup vs baseline: 1.1858x; 1.1166x over previous
//
#include <hip/hip_runtime.h>
#include <cstdint>
#include <cstddef>

#define NB 16
#define TT 12
#define NN 1024
#define DD 64
#define FF 64
#define JT 768   // T*D

__device__ __forceinline__ float sigmoidf_(float v) { return 1.0f / (1.0f + expf(-v)); }

__device__ __forceinline__ void gload16(const float* g, float* lds) {
    __builtin_amdgcn_global_load_lds(
        (const __attribute__((address_space(1))) void*)g,
        (__attribute__((address_space(3))) void*)lds, 16, 0, 0);
}

// ---------------- A transpose: At[b][v][w] = A[b][w][v] ----------------
__global__ __launch_bounds__(256) void transpose_A(
    const float* __restrict__ A, float* __restrict__ At)
{
    __shared__ float tile[64][65];
    const int b = blockIdx.z;
    const int w0 = blockIdx.x * 64;
    const int v0 = blockIdx.y * 64;
    const int tid = threadIdx.x;
    const int r  = tid >> 2;
    const int c0 = (tid & 3) * 16;
    const float* Ab = A + (size_t)b * NN * NN;
    float* Atb = At + (size_t)b * NN * NN;
#pragma unroll
    for (int p = 0; p < 4; ++p) {
        const float4 v = *(const float4*)&Ab[(size_t)(w0 + r) * NN + v0 + c0 + p * 4];
        tile[r][c0 + p * 4 + 0] = v.x; tile[r][c0 + p * 4 + 1] = v.y;
        tile[r][c0 + p * 4 + 2] = v.z; tile[r][c0 + p * 4 + 3] = v.w;
    }
    __syncthreads();
#pragma unroll
    for (int p = 0; p < 4; ++p) {
        float4 v;
        v.x = tile[c0 + p * 4 + 0][r]; v.y = tile[c0 + p * 4 + 1][r];
        v.z = tile[c0 + p * 4 + 2][r]; v.w = tile[c0 + p * 4 + 3][r];
        *(float4*)&Atb[(size_t)(v0 + r) * NN + w0 + c0 + p * 4] = v;
    }
}

// ---------------- propagation GEMM: Xout[b] = A[b] @ Xin[b] ----------------
// BK=16 double-buffered. ATRANS: Aop = At (k-major), global_load_lds staging,
// linear [16][128] tiles, 32KB LDS total -> 4 blocks/CU.
// XFROMX: Xin = x (B,T,N,D), col j -> (t=j/64, d=j%64); else (B,N,768).
template<bool XFROMX, bool ATRANS>
__global__ __launch_bounds__(256, 4) void gemm_prop(
    const float* __restrict__ Aop, const float* __restrict__ Xin,
    float* __restrict__ Xout)
{
    constexpr int AST = ATRANS ? 128 : 132;
    __shared__ float As[2][16 * AST];
    __shared__ float Bs[2][16 * 128];

    // bijective XCD swizzle: 768 blocks, 96 per XCD -> each XCD owns 2 batches
    const int wg  = blockIdx.x;
    const int nlin = (wg & 7) * 96 + (wg >> 3);
    const int b  = nlin / 48;
    const int rr = nlin % 48;
    const int rb = rr / 6, cb = rr % 6;
    const int w0 = rb * 128, j0 = cb * 128;

    const int tid = threadIdx.x, lane = tid & 63, wid = tid >> 6;
    const int rg = tid >> 4, cg = tid & 15;
    const int row0 = rg * 8;

    auto stage = [&](int buf, int kt) {
        if constexpr (ATRANS) {
            // A: 8 chunks of 1KB; chunk c = k rows {2c, 2c+1}; wave wid does c=wid*2+p
            const float* abase = Aop + ((size_t)b * NN + (size_t)kt * 16) * NN + w0;
#pragma unroll
            for (int p = 0; p < 2; ++p) {
                const int c = wid * 2 + p;
                const int k = 2 * c + (lane >> 5);
                gload16(abase + (size_t)k * NN + (lane & 31) * 4, &As[buf][c * 256]);
            }
#pragma unroll
            for (int p = 0; p < 2; ++p) {
                const int c = wid * 2 + p;
                const int k = 2 * c + (lane >> 5);        // row within tile 0..15
                const float* g;
                if constexpr (XFROMX) {
                    const int jj = (lane & 31) * 4;
                    const int t = cb * 2 + (jj >> 6);
                    const int d = jj & 63;
                    g = Xin + (((size_t)b * TT + t) * NN + (size_t)kt * 16 + k) * DD + d;
                } else {
                    g = Xin + ((size_t)b * NN + (size_t)kt * 16 + k) * JT + j0 + (lane & 31) * 4;
                }
                gload16(g, &Bs[buf][c * 256]);
            }
        } else {
            const float* Ab = Aop + (size_t)b * NN * NN;
#pragma unroll
            for (int p = 0; p < 2; ++p) {
                const int c  = tid + p * 256;
                const int w  = c >> 2;
                const int k4 = (c & 3) * 4;
                const float4 v = *(const float4*)&Ab[(size_t)(w0 + w) * NN + kt * 16 + k4];
                As[buf][(k4 + 0) * 132 + w] = v.x;
                As[buf][(k4 + 1) * 132 + w] = v.y;
                As[buf][(k4 + 2) * 132 + w] = v.z;
                As[buf][(k4 + 3) * 132 + w] = v.w;
            }
#pragma unroll
            for (int p = 0; p < 2; ++p) {
                const int c = tid + p * 256;
                const int k = c >> 5;
                const int j = (c & 31) * 4;
                float4 v;
                if constexpr (XFROMX) {
                    const int t = cb * 2 + (j >> 6);
                    const int d = j & 63;
                    v = *(const float4*)&Xin[(((size_t)b * TT + t) * NN + (size_t)kt * 16 + k) * DD + d];
                } else {
                    v = *(const float4*)&Xin[((size_t)b * NN + (size_t)kt * 16 + k) * JT + j0 + j];
                }
                *(float4*)&Bs[buf][k * 128 + j] = v;
            }
        }
    };

    float acc[8][8];
#pragma unroll
    for (int i = 0; i < 8; ++i)
#pragma unroll
        for (int j = 0; j < 8; ++j) acc[i][j] = 0.0f;

    stage(0, 0);
    __syncthreads();            // drains tile-0 loads
    int cur = 0;
    for (int kt = 0; kt < 64; ++kt) {
        if (kt + 1 < 64) stage(cur ^ 1, kt + 1);   // prefetch next tile (overlaps compute)
#pragma unroll
        for (int k = 0; k < 16; ++k) {
            float a[8], bb[8];
            *(float4*)&a[0]  = *(const float4*)&As[cur][k * AST + row0];
            *(float4*)&a[4]  = *(const float4*)&As[cur][k * AST + row0 + 4];
            *(float4*)&bb[0] = *(const float4*)&Bs[cur][k * 128 + cg * 4];
            *(float4*)&bb[4] = *(const float4*)&Bs[cur][k * 128 + 64 + cg * 4];
#pragma unroll
            for (int i = 0; i < 8; ++i)
#pragma unroll
                for (int j = 0; j < 8; ++j)
                    acc[i][j] = fmaf(a[i], bb[j], acc[i][j]);
        }
        __syncthreads();        // drains prefetch + fences cur reads
        cur ^= 1;
    }
#pragma unroll
    for (int i = 0; i < 8; ++i) {
        float4 v0 = {acc[i][0], acc[i][1], acc[i][2], acc[i][3]};
        float4 v1 = {acc[i][4], acc[i][5], acc[i][6], acc[i][7]};
        float* dst = Xout + ((size_t)b * NN + w0 + row0 + i) * JT + j0;
        *(float4*)&dst[cg * 4]      = v0;
        *(float4*)&dst[64 + cg * 4] = v1;
    }
}

// ---------------- conv (BTN x 192 @ 192 x 64) + BN + ReLU ----------------
__global__ __launch_bounds__(256) void conv_bn_relu(
    const float* __restrict__ x,  const float* __restrict__ X1,
    const float* __restrict__ X2, const float* __restrict__ W,
    const float* __restrict__ convb, const float* __restrict__ gamma,
    const float* __restrict__ beta,  const float* __restrict__ mean,
    const float* __restrict__ var,   float* __restrict__ y)
{
    __shared__ float As[64][132];
    __shared__ float Ws[64][68];
    const int nb = blockIdx.x, t = blockIdx.y, b = blockIdx.z;
    const int n0 = nb * 128;
    const int tid = threadIdx.x;
    const int rg = tid >> 4, cg = tid & 15;
    const int row0 = rg * 8, f0 = cg * 4;

    float acc[8][4];
#pragma unroll
    for (int i = 0; i < 8; ++i)
#pragma unroll
        for (int j = 0; j < 4; ++j) acc[i][j] = 0.0f;

    for (int kt = 0; kt < 3; ++kt) {
        const float* src;
        size_t rstride;
        if (kt == 0) { src = x + (((size_t)b * TT + t) * NN + n0) * DD; rstride = DD; }
        else {
            const float* Xk = (kt == 1) ? X1 : X2;
            src = Xk + ((size_t)b * NN + n0) * JT + t * DD; rstride = JT;
        }
        __syncthreads();
#pragma unroll
        for (int p = 0; p < 8; ++p) {
            const int row = (tid >> 4) + p * 16;
            const int c4  = (tid & 15) * 4;
            const float4 v = *(const float4*)&src[(size_t)row * rstride + c4];
            As[c4 + 0][row] = v.x; As[c4 + 1][row] = v.y;
            As[c4 + 2][row] = v.z; As[c4 + 3][row] = v.w;
        }
#pragma unroll
        for (int p = 0; p < 4; ++p) {
            const int f  = (tid >> 4) + p * 16;
            const int c4 = (tid & 15) * 4;
            const float4 v = *(const float4*)&W[f * 192 + kt * 64 + c4];
            Ws[c4 + 0][f] = v.x; Ws[c4 + 1][f] = v.y;
            Ws[c4 + 2][f] = v.z; Ws[c4 + 3][f] = v.w;
        }
        __syncthreads();
#pragma unroll
        for (int k = 0; k < 64; ++k) {
            float a[8], w[4];
            *(float4*)&a[0] = *(const float4*)&As[k][row0];
            *(float4*)&a[4] = *(const float4*)&As[k][row0 + 4];
            *(float4*)&w[0] = *(const float4*)&Ws[k][f0];
#pragma unroll
            for (int i = 0; i < 8; ++i)
#pragma unroll
                for (int j = 0; j < 4; ++j)
                    acc[i][j] = fmaf(a[i], w[j], acc[i][j]);
        }
    }
    float s[4], off[4];
#pragma unroll
    for (int j = 0; j < 4; ++j) {
        const int f = f0 + j;
        const float sc = gamma[f] / sqrtf(var[f] + 1e-5f);
        s[j]   = sc;
        off[j] = (convb[f] - mean[f]) * sc + beta[f];
    }
#pragma unroll
    for (int i = 0; i < 8; ++i) {
        float4 v;
        v.x = fmaxf(acc[i][0] * s[0] + off[0], 0.0f);
        v.y = fmaxf(acc[i][1] * s[1] + off[1], 0.0f);
        v.z = fmaxf(acc[i][2] * s[2] + off[2], 0.0f);
        v.w = fmaxf(acc[i][3] * s[3] + off[3], 0.0f);
        *(float4*)&y[(((size_t)b * TT + t) * NN + n0 + row0 + i) * FF + f0] = v;
    }
}

// ---------------- fused GRU, all 12 steps in one kernel ----------------
__global__ __launch_bounds__(256) void gru_all(
    const float* __restrict__ y,    const float* __restrict__ wff,
    const float* __restrict__ bff,  const float* __restrict__ wzff,
    const float* __restrict__ bzff, float* __restrict__ out)
{
    __shared__ float Xs[64][36];
    __shared__ float Hs[64][36];
    __shared__ float Rs[64][36];
    __shared__ float Us[64][36];
    __shared__ float Ws[64][132];
    const int tid = threadIdx.x;
    const int mb  = blockIdx.x;
    const int b = mb >> 5, n0 = (mb & 31) * 32;
    const int rg = tid >> 5;
    const int og = tid & 31;

    for (int i = tid; i < 64 * 36; i += 256) (&Hs[0][0])[i] = 0.0f;

    for (int t = 0; t < TT; ++t) {
        {
            const float* xt = y + (((size_t)b * TT + t) * NN + n0) * DD;
            const int m = tid >> 3, c0 = (tid & 7) * 8;
            const float4 v0 = *(const float4*)&xt[m * DD + c0];
            const float4 v1 = *(const float4*)&xt[m * DD + c0 + 4];
            Xs[c0 + 0][m] = v0.x; Xs[c0 + 1][m] = v0.y;
            Xs[c0 + 2][m] = v0.z; Xs[c0 + 3][m] = v0.w;
            Xs[c0 + 4][m] = v1.x; Xs[c0 + 5][m] = v1.y;
            Xs[c0 + 6][m] = v1.z; Xs[c0 + 7][m] = v1.w;
        }
        float acc[4][4];
#pragma unroll
        for (int i = 0; i < 4; ++i)
#pragma unroll
            for (int j = 0; j < 4; ++j) acc[i][j] = 0.0f;

#pragma unroll
        for (int half = 0; half < 2; ++half) {
            __syncthreads();
#pragma unroll
            for (int p = 0; p < 8; ++p) {
                const int kk = (tid >> 5) + p * 8;
                const int o4 = (tid & 31) * 4;
                *(float4*)&Ws[kk][o4] =
                    *(const float4*)&wff[((size_t)t * 128 + half * 64 + kk) * 128 + o4];
            }
            __syncthreads();
            const float (*Asrc)[36] = half ? Hs : Xs;
#pragma unroll 4
            for (int kk = 0; kk < 64; ++kk) {
                const float4 av = *(const float4*)&Asrc[kk][rg * 4];
                const float4 wv = *(const float4*)&Ws[kk][og * 4];
                const float a0 = av.x, a1 = av.y, a2 = av.z, a3 = av.w;
                acc[0][0] = fmaf(a0, wv.x, acc[0][0]); acc[0][1] = fmaf(a0, wv.y, acc[0][1]);
                acc[0][2] = fmaf(a0, wv.z, acc[0][2]); acc[0][3] = fmaf(a0, wv.w, acc[0][3]);
                acc[1][0] = fmaf(a1, wv.x, acc[1][0]); acc[1][1] = fmaf(a1, wv.y, acc[1][1]);
                acc[1][2] = fmaf(a1, wv.z, acc[1][2]); acc[1][3] = fmaf(a1, wv.w, acc[1][3]);
                acc[2][0] = fmaf(a2, wv.x, acc[2][0]); acc[2][1] = fmaf(a2, wv.y, acc[2][1]);
                acc[2][2] = fmaf(a2, wv.z, acc[2][2]); acc[2][3] = fmaf(a2, wv.w, acc[2][3]);
                acc[3][0] = fmaf(a3, wv.x, acc[3][0]); acc[3][1] = fmaf(a3, wv.y, acc[3][1]);
                acc[3][2] = fmaf(a3, wv.z, acc[3][2]); acc[3][3] = fmaf(a3, wv.w, acc[3][3]);
            }
        }
        {
            const float4 bb4 = *(const float4*)&bff[(size_t)t * 128 + og * 4];
            float g[4][4];
#pragma unroll
            for (int i = 0; i < 4; ++i) {
                g[i][0] = sigmoidf_(acc[i][0] + bb4.x);
                g[i][1] = sigmoidf_(acc[i][1] + bb4.y);
                g[i][2] = sigmoidf_(acc[i][2] + bb4.z);
                g[i][3] = sigmoidf_(acc[i][3] + bb4.w);
            }
            if (og < 16) {
#pragma unroll
                for (int i = 0; i < 4; ++i)
#pragma unroll
                    for (int j = 0; j < 4; ++j) {
                        const int f = og * 4 + j, m = rg * 4 + i;
                        Rs[f][m] = g[i][j] * Hs[f][m];
                    }
            } else {
#pragma unroll
                for (int i = 0; i < 4; ++i)
#pragma unroll
                    for (int j = 0; j < 4; ++j)
                        Us[og * 4 + j - 64][rg * 4 + i] = g[i][j];
            }
        }
        float accz[4][2];
#pragma unroll
        for (int i = 0; i < 4; ++i) { accz[i][0] = 0.0f; accz[i][1] = 0.0f; }

#pragma unroll
        for (int half = 0; half < 2; ++half) {
            __syncthreads();
#pragma unroll
            for (int p = 0; p < 4; ++p) {
                const int kk = (tid >> 4) + p * 16;
                const int f4 = (tid & 15) * 4;
                *(float4*)&Ws[kk][f4] =
                    *(const float4*)&wzff[((size_t)t * 128 + half * 64 + kk) * 64 + f4];
            }
            __syncthreads();
            const float (*Asrc)[36] = half ? Rs : Xs;
#pragma unroll 4
            for (int kk = 0; kk < 64; ++kk) {
                const float4 av = *(const float4*)&Asrc[kk][rg * 4];
                const float2 wv = *(const float2*)&Ws[kk][og * 2];
                accz[0][0] = fmaf(av.x, wv.x, accz[0][0]); accz[0][1] = fmaf(av.x, wv.y, accz[0][1]);
                accz[1][0] = fmaf(av.y, wv.x, accz[1][0]); accz[1][1] = fmaf(av.y, wv.y, accz[1][1]);
                accz[2][0] = fmaf(av.z, wv.x, accz[2][0]); accz[2][1] = fmaf(av.z, wv.y, accz[2][1]);
                accz[3][0] = fmaf(av.w, wv.x, accz[3][0]); accz[3][1] = fmaf(av.w, wv.y, accz[3][1]);
            }
        }
        {
            const float2 bz = *(const float2*)&bzff[(size_t)t * 64 + og * 2];
            const int f0_ = og * 2;
#pragma unroll
            for (int i = 0; i < 4; ++i) {
                const int m = rg * 4 + i;
                const float z0 = tanhf(accz[i][0] + bz.x);
                const float z1 = tanhf(accz[i][1] + bz.y);
                const float u0 = Us[f0_][m],     u1 = Us[f0_ + 1][m];
                const float h0 = Hs[f0_][m],     h1 = Hs[f0_ + 1][m];
                const float hn0 = u0 * z0 + (1.0f - u0) * h0;
                const float hn1 = u1 * z1 + (1.0f - u1) * h1;
                Hs[f0_][m] = hn0; Hs[f0_ + 1][m] = hn1;
                *(float2*)&out[(((size_t)b * TT + t) * NN + n0 + m) * FF + f0_] =
                    make_float2(hn0, hn1);
            }
        }
        __syncthreads();
    }
}

extern "C" void kernel_launch(void* const* d_in, const int* in_sizes, int n_in,
                              void* d_out, int out_size, void* d_ws, size_t ws_size,
                              hipStream_t stream)
{
    const float* x        = (const float*)d_in[0];
    const float* A        = (const float*)d_in[1];
    const float* conv_w   = (const float*)d_in[2];
    const float* conv_b   = (const float*)d_in[3];
    const float* bn_gamma = (const float*)d_in[4];
    const float* bn_beta  = (const float*)d_in[5];
    const float* bn_mean  = (const float*)d_in[6];
    const float* bn_var   = (const float*)d_in[7];
    const float* gru_ff_w  = (const float*)d_in[8];
    const float* gru_ff_b  = (const float*)d_in[9];
    const float* gru_zff_w = (const float*)d_in[10];
    const float* gru_zff_b = (const float*)d_in[11];
    float* out = (float*)d_out;
    float* ws  = (float*)d_ws;

    const size_t szX = (size_t)NB * NN * JT;     // 12.58M floats
    const size_t szA = (size_t)NB * NN * NN;     // 16.78M floats
    float* X1 = ws;
    float* X2 = ws + szX;

    const bool useAt = ws_size >= (2 * szX + szA) * sizeof(float);
    dim3 gconv(8, TT, NB);

    if (useAt) {
        float* At = ws + 2 * szX;
        float* yb = At;                 // y aliases At: At is dead after gemm2
        transpose_A<<<dim3(16, 16, NB), 256, 0, stream>>>(A, At);
        gemm_prop<true,  true><<<768, 256, 0, stream>>>(At, x,  X1);
        gemm_prop<false, true><<<768, 256, 0, stream>>>(At, X1, X2);
        conv_bn_relu<<<gconv, 256, 0, stream>>>(x, X1, X2, conv_w, conv_b,
                                                bn_gamma, bn_beta, bn_mean, bn_var, yb);
        gru_all<<<512, 256, 0, stream>>>(yb, gru_ff_w, gru_ff_b,
                                         gru_zff_w, gru_zff_b, out);
    } else {
        float* yb = ws + 2 * szX;
        gemm_prop<true,  false><<<768, 256, 0, stream>>>(A, x,  X1);
        gemm_prop<false, false><<<768, 256, 0, stream>>>(A, X1, X2);
        conv_bn_relu<<<gconv, 256, 0, stream>>>(x, X1, X2, conv_w, conv_b,
                                                bn_gamma, bn_beta, bn_mean, bn_var, yb);
        gru_all<<<512, 256, 0, stream>>>(yb, gru_ff_w, gru_ff_b,
                                         gru_zff_w, gru_zff_b, out);
    }
}

// Round 4
// 523.937 us; speedup vs baseline: 2.0173x; 1.7012x over previous
//
#include <hip/hip_runtime.h>
#include <cstdint>
#include <cstddef>

#define NB 16
#define TT 12
#define NN 1024
#define DD 64
#define FF 64
#define JT 768   // T*D

typedef __attribute__((ext_vector_type(8))) short v8s;
typedef __attribute__((ext_vector_type(4))) short v4s;
typedef __attribute__((ext_vector_type(4))) float v4f;

__device__ __forceinline__ float sigmoidf_(float v) { return 1.0f / (1.0f + expf(-v)); }

__device__ __forceinline__ float bf2f(unsigned short h) {
    union { unsigned int u; float f; } x; x.u = ((unsigned int)h) << 16; return x.f;
}
__device__ __forceinline__ unsigned short f2bf(float f) {
    union { float f; unsigned int u; } x; x.f = f;
    return (unsigned short)((x.u + 0x7fffu + ((x.u >> 16) & 1u)) >> 16);
}

__device__ __forceinline__ void gload16(const void* g, void* lds) {
    __builtin_amdgcn_global_load_lds(
        (const __attribute__((address_space(1))) void*)g,
        (__attribute__((address_space(3))) void*)lds, 16, 0, 0);
}

// ---------------- split A (fp32 row-major) -> Ah, Al bf16 row-major ----------
__global__ __launch_bounds__(256) void split_A(
    const float* __restrict__ A, unsigned short* __restrict__ Ah,
    unsigned short* __restrict__ Al)
{
    const size_t i0 = ((size_t)blockIdx.x * 256 + threadIdx.x) * 16;
    float v[16];
#pragma unroll
    for (int s = 0; s < 4; ++s)
        *(float4*)&v[s * 4] = *(const float4*)&A[i0 + s * 4];
    v8s h0, h1, l0, l1;
#pragma unroll
    for (int q = 0; q < 8; ++q) {
        unsigned short h = f2bf(v[q]);
        h0[q] = (short)h; l0[q] = (short)f2bf(v[q] - bf2f(h));
    }
#pragma unroll
    for (int q = 0; q < 8; ++q) {
        unsigned short h = f2bf(v[8 + q]);
        h1[q] = (short)h; l1[q] = (short)f2bf(v[8 + q] - bf2f(h));
    }
    *(v8s*)&Ah[i0] = h0; *(v8s*)&Ah[i0 + 8] = h1;
    *(v8s*)&Al[i0] = l0; *(v8s*)&Al[i0 + 8] = l1;
}

// ------ split+transpose x (B,T,N,D) fp32 -> xTh,xTl (B, 768, 1024) bf16 ------
__global__ __launch_bounds__(256) void xsplitT(
    const float* __restrict__ x, unsigned short* __restrict__ Th,
    unsigned short* __restrict__ Tl)
{
    __shared__ float tile[64][68];
    const int v0 = blockIdx.x * 64, t = blockIdx.y, b = blockIdx.z;
    const int tid = threadIdx.x;
    {
        const int r = tid >> 2, q = (tid & 3) * 16;
#pragma unroll
        for (int s = 0; s < 4; ++s) {
            const float4 w = *(const float4*)&x[(((size_t)b * TT + t) * NN + v0 + r) * DD + q + s * 4];
            tile[r][q + s * 4 + 0] = w.x; tile[r][q + s * 4 + 1] = w.y;
            tile[r][q + s * 4 + 2] = w.z; tile[r][q + s * 4 + 3] = w.w;
        }
    }
    __syncthreads();
    {
        const int d = tid >> 2, vc = (tid & 3) * 16;
        const size_t base = ((size_t)b * JT + t * 64 + d) * 1024 + v0 + vc;
        v8s h0, h1, l0, l1;
#pragma unroll
        for (int s = 0; s < 8; ++s) {
            const float f = tile[vc + s][d];
            unsigned short h = f2bf(f);
            h0[s] = (short)h; l0[s] = (short)f2bf(f - bf2f(h));
        }
#pragma unroll
        for (int s = 0; s < 8; ++s) {
            const float f = tile[vc + 8 + s][d];
            unsigned short h = f2bf(f);
            h1[s] = (short)h; l1[s] = (short)f2bf(f - bf2f(h));
        }
        *(v8s*)&Th[base] = h0; *(v8s*)&Th[base + 8] = h1;
        *(v8s*)&Tl[base] = l0; *(v8s*)&Tl[base + 8] = l1;
    }
}

// -------- bf16 split-2 MFMA GEMM: C[b][n][m] = sum_k A[b][m][k] * B[b][n][k] --
// A: (B,1024,1024) bf16 pairs row-major; B: (B,768,1024) bf16 pairs.
// PAIROUT: write Ch/Cl bf16 pairs (B,768,1024); else Cf fp32 (B,768,1024).
// 3 products: AhBh + AhBl + AlBh, fp32 MFMA accumulate.
template<bool PAIROUT>
__global__ __launch_bounds__(256, 2) void gemm_bf(
    const unsigned short* __restrict__ Ah, const unsigned short* __restrict__ Al,
    const unsigned short* __restrict__ Bh, const unsigned short* __restrict__ Bl,
    unsigned short* __restrict__ Ch, unsigned short* __restrict__ Cl,
    float* __restrict__ Cf)
{
    __shared__ unsigned short LA[2][2][4096];   // [buf][hi/lo][128m x 32k]
    __shared__ unsigned short LB[2][2][4096];   // [buf][hi/lo][128n x 32k]

    // bijective XCD swizzle: 768 blocks, 96 per XCD
    const int wg = blockIdx.x;
    const int nlin = (wg & 7) * 96 + (wg >> 3);
    const int b  = nlin / 48;
    const int rr = nlin % 48;
    const int m0 = (rr / 6) * 128, n0 = (rr % 6) * 128;

    const int tid = threadIdx.x, lane = tid & 63, wid = tid >> 6;
    const int lr = lane & 15, hi = lane >> 4;
    const int wr = wid >> 1, wc = wid & 1;

    auto stage = [&](int buf, int kt) {
        const int rA = lane >> 2, kc = (lane & 3) * 8;
#pragma unroll
        for (int p = 0; p < 2; ++p) {
            const int c = wid * 2 + p;
            const size_t ga = ((size_t)b * 1024 + m0 + c * 16 + rA) * 1024 + kt * 32 + kc;
            gload16(Ah + ga, &LA[buf][0][c * 512]);
            gload16(Al + ga, &LA[buf][1][c * 512]);
            const size_t gb = ((size_t)b * JT + n0 + c * 16 + rA) * 1024 + kt * 32 + kc;
            gload16(Bh + gb, &LB[buf][0][c * 512]);
            gload16(Bl + gb, &LB[buf][1][c * 512]);
        }
    };

    v4f acc[4][4];
#pragma unroll
    for (int i = 0; i < 4; ++i)
#pragma unroll
        for (int j = 0; j < 4; ++j) acc[i][j] = (v4f){0.f, 0.f, 0.f, 0.f};

    stage(0, 0);
    __syncthreads();
    int cur = 0;
    for (int kt = 0; kt < 32; ++kt) {
        if (kt + 1 < 32) stage(cur ^ 1, kt + 1);
        v8s ah[4], al[4], bh[4], bl[4];
#pragma unroll
        for (int f = 0; f < 4; ++f) {
            const int m = wr * 64 + f * 16 + lr;
            ah[f] = *(const v8s*)&LA[cur][0][m * 32 + hi * 8];
            al[f] = *(const v8s*)&LA[cur][1][m * 32 + hi * 8];
        }
#pragma unroll
        for (int f = 0; f < 4; ++f) {
            const int n = wc * 64 + f * 16 + lr;
            bh[f] = *(const v8s*)&LB[cur][0][n * 32 + hi * 8];
            bl[f] = *(const v8s*)&LB[cur][1][n * 32 + hi * 8];
        }
#pragma unroll
        for (int fi = 0; fi < 4; ++fi)
#pragma unroll
            for (int fj = 0; fj < 4; ++fj) {
                acc[fi][fj] = __builtin_amdgcn_mfma_f32_16x16x32_bf16(ah[fi], bh[fj], acc[fi][fj], 0, 0, 0);
                acc[fi][fj] = __builtin_amdgcn_mfma_f32_16x16x32_bf16(ah[fi], bl[fj], acc[fi][fj], 0, 0, 0);
                acc[fi][fj] = __builtin_amdgcn_mfma_f32_16x16x32_bf16(al[fi], bh[fj], acc[fi][fj], 0, 0, 0);
            }
        __syncthreads();
        cur ^= 1;
    }

    // C/D layout (m89): col = lane&15, row = (lane>>4)*4 + reg
#pragma unroll
    for (int fi = 0; fi < 4; ++fi)
#pragma unroll
        for (int fj = 0; fj < 4; ++fj) {
            const int n  = n0 + wc * 64 + fj * 16 + lr;
            const int mb = m0 + wr * 64 + fi * 16 + hi * 4;
            const size_t o = ((size_t)b * JT + n) * 1024 + mb;
            if (PAIROUT) {
                v4s vh, vl;
#pragma unroll
                for (int r = 0; r < 4; ++r) {
                    const float v = acc[fi][fj][r];
                    const unsigned short h = f2bf(v);
                    vh[r] = (short)h; vl[r] = (short)f2bf(v - bf2f(h));
                }
                *(v4s*)&Ch[o] = vh;
                *(v4s*)&Cl[o] = vl;
            } else {
                float4 v = {acc[fi][fj][0], acc[fi][fj][1], acc[fi][fj][2], acc[fi][fj][3]};
                *(float4*)&Cf[o] = v;
            }
        }
}

// -------------- fallback fp32 GEMM (R3 proven, reg-transpose staging) --------
template<bool XFROMX>
__global__ __launch_bounds__(256, 4) void gemm_f32(
    const float* __restrict__ Aop, const float* __restrict__ Xin,
    float* __restrict__ Xout)
{
    __shared__ float As[2][16 * 132];
    __shared__ float Bs[2][16 * 128];
    const int wg  = blockIdx.x;
    const int nlin = (wg & 7) * 96 + (wg >> 3);
    const int b  = nlin / 48;
    const int rr = nlin % 48;
    const int rb = rr / 6, cb = rr % 6;
    const int w0 = rb * 128, j0 = cb * 128;
    const int tid = threadIdx.x;
    const int rg = tid >> 4, cg = tid & 15;
    const int row0 = rg * 8;

    auto stage = [&](int buf, int kt) {
        const float* Ab = Aop + (size_t)b * NN * NN;
#pragma unroll
        for (int p = 0; p < 2; ++p) {
            const int c  = tid + p * 256;
            const int w  = c >> 2;
            const int k4 = (c & 3) * 4;
            const float4 v = *(const float4*)&Ab[(size_t)(w0 + w) * NN + kt * 16 + k4];
            As[buf][(k4 + 0) * 132 + w] = v.x;
            As[buf][(k4 + 1) * 132 + w] = v.y;
            As[buf][(k4 + 2) * 132 + w] = v.z;
            As[buf][(k4 + 3) * 132 + w] = v.w;
        }
#pragma unroll
        for (int p = 0; p < 2; ++p) {
            const int c = tid + p * 256;
            const int k = c >> 5;
            const int j = (c & 31) * 4;
            float4 v;
            if (XFROMX) {
                const int t = cb * 2 + (j >> 6);
                const int d = j & 63;
                v = *(const float4*)&Xin[(((size_t)b * TT + t) * NN + (size_t)kt * 16 + k) * DD + d];
            } else {
                v = *(const float4*)&Xin[((size_t)b * NN + (size_t)kt * 16 + k) * JT + j0 + j];
            }
            *(float4*)&Bs[buf][k * 128 + j] = v;
        }
    };

    float acc[8][8];
#pragma unroll
    for (int i = 0; i < 8; ++i)
#pragma unroll
        for (int j = 0; j < 8; ++j) acc[i][j] = 0.0f;

    stage(0, 0);
    __syncthreads();
    int cur = 0;
    for (int kt = 0; kt < 64; ++kt) {
        if (kt + 1 < 64) stage(cur ^ 1, kt + 1);
#pragma unroll
        for (int k = 0; k < 16; ++k) {
            float a[8], bb[8];
            *(float4*)&a[0]  = *(const float4*)&As[cur][k * 132 + row0];
            *(float4*)&a[4]  = *(const float4*)&As[cur][k * 132 + row0 + 4];
            *(float4*)&bb[0] = *(const float4*)&Bs[cur][k * 128 + cg * 4];
            *(float4*)&bb[4] = *(const float4*)&Bs[cur][k * 128 + 64 + cg * 4];
#pragma unroll
            for (int i = 0; i < 8; ++i)
#pragma unroll
                for (int j = 0; j < 8; ++j)
                    acc[i][j] = fmaf(a[i], bb[j], acc[i][j]);
        }
        __syncthreads();
        cur ^= 1;
    }
#pragma unroll
    for (int i = 0; i < 8; ++i) {
        float4 v0 = {acc[i][0], acc[i][1], acc[i][2], acc[i][3]};
        float4 v1 = {acc[i][4], acc[i][5], acc[i][6], acc[i][7]};
        float* dst = Xout + ((size_t)b * NN + w0 + row0 + i) * JT + j0;
        *(float4*)&dst[cg * 4]      = v0;
        *(float4*)&dst[64 + cg * 4] = v1;
    }
}

// ---------------- conv (BTN x 192 @ 192 x 64) + BN + ReLU ----------------
// PAIRS: X1 as bf16 pairs [b][768][1024], X2 as fp32 [b][768][1024].
// else:  X1f/X2f fp32 row-major (B, N, 768)  (fallback).
template<bool PAIRS>
__global__ __launch_bounds__(256) void conv_bn_relu(
    const float* __restrict__ x,
    const unsigned short* __restrict__ X1h, const unsigned short* __restrict__ X1l,
    const float* __restrict__ X2T,
    const float* __restrict__ X1f, const float* __restrict__ X2f,
    const float* __restrict__ W,
    const float* __restrict__ convb, const float* __restrict__ gamma,
    const float* __restrict__ beta,  const float* __restrict__ mean,
    const float* __restrict__ var,   float* __restrict__ y)
{
    __shared__ float As[64][132];
    __shared__ float Ws[64][68];
    const int nb = blockIdx.x, t = blockIdx.y, b = blockIdx.z;
    const int n0 = nb * 128;
    const int tid = threadIdx.x;
    const int rg = tid >> 4, cg = tid & 15;
    const int row0 = rg * 8, f0 = cg * 4;

    float acc[8][4];
#pragma unroll
    for (int i = 0; i < 8; ++i)
#pragma unroll
        for (int j = 0; j < 4; ++j) acc[i][j] = 0.0f;

    for (int kt = 0; kt < 3; ++kt) {
        __syncthreads();
        if (kt == 0) {
            const float* src = x + (((size_t)b * TT + t) * NN + n0) * DD;
#pragma unroll
            for (int p = 0; p < 8; ++p) {
                const int row = (tid >> 4) + p * 16;
                const int c4  = (tid & 15) * 4;
                const float4 v = *(const float4*)&src[(size_t)row * DD + c4];
                As[c4 + 0][row] = v.x; As[c4 + 1][row] = v.y;
                As[c4 + 2][row] = v.z; As[c4 + 3][row] = v.w;
            }
        } else if (PAIRS) {
            if (kt == 1) {
#pragma unroll
                for (int p = 0; p < 4; ++p) {
                    const int pos = p * 256 + tid;
                    const int c = pos >> 4, rw = (pos & 15) * 8;
                    const size_t o = ((size_t)b * JT + t * 64 + c) * 1024 + n0 + rw;
                    const v8s hv = *(const v8s*)&X1h[o];
                    const v8s lv = *(const v8s*)&X1l[o];
#pragma unroll
                    for (int q = 0; q < 8; ++q)
                        As[c][rw + q] = bf2f((unsigned short)hv[q]) + bf2f((unsigned short)lv[q]);
                }
            } else {
#pragma unroll
                for (int p = 0; p < 8; ++p) {
                    const int pos = p * 256 + tid;
                    const int c = pos >> 5, rw = (pos & 31) * 4;
                    const float4 v = *(const float4*)&X2T[((size_t)b * JT + t * 64 + c) * 1024 + n0 + rw];
                    As[c][rw + 0] = v.x; As[c][rw + 1] = v.y;
                    As[c][rw + 2] = v.z; As[c][rw + 3] = v.w;
                }
            }
        } else {
            const float* src = ((kt == 1) ? X1f : X2f) + ((size_t)b * NN + n0) * JT + t * DD;
#pragma unroll
            for (int p = 0; p < 8; ++p) {
                const int row = (tid >> 4) + p * 16;
                const int c4  = (tid & 15) * 4;
                const float4 v = *(const float4*)&src[(size_t)row * JT + c4];
                As[c4 + 0][row] = v.x; As[c4 + 1][row] = v.y;
                As[c4 + 2][row] = v.z; As[c4 + 3][row] = v.w;
            }
        }
#pragma unroll
        for (int p = 0; p < 4; ++p) {
            const int f  = (tid >> 4) + p * 16;
            const int c4 = (tid & 15) * 4;
            const float4 v = *(const float4*)&W[f * 192 + kt * 64 + c4];
            Ws[c4 + 0][f] = v.x; Ws[c4 + 1][f] = v.y;
            Ws[c4 + 2][f] = v.z; Ws[c4 + 3][f] = v.w;
        }
        __syncthreads();
#pragma unroll
        for (int k = 0; k < 64; ++k) {
            float a[8], w[4];
            *(float4*)&a[0] = *(const float4*)&As[k][row0];
            *(float4*)&a[4] = *(const float4*)&As[k][row0 + 4];
            *(float4*)&w[0] = *(const float4*)&Ws[k][f0];
#pragma unroll
            for (int i = 0; i < 8; ++i)
#pragma unroll
                for (int j = 0; j < 4; ++j)
                    acc[i][j] = fmaf(a[i], w[j], acc[i][j]);
        }
    }
    float s[4], off[4];
#pragma unroll
    for (int j = 0; j < 4; ++j) {
        const int f = f0 + j;
        const float sc = gamma[f] / sqrtf(var[f] + 1e-5f);
        s[j]   = sc;
        off[j] = (convb[f] - mean[f]) * sc + beta[f];
    }
#pragma unroll
    for (int i = 0; i < 8; ++i) {
        float4 v;
        v.x = fmaxf(acc[i][0] * s[0] + off[0], 0.0f);
        v.y = fmaxf(acc[i][1] * s[1] + off[1], 0.0f);
        v.z = fmaxf(acc[i][2] * s[2] + off[2], 0.0f);
        v.w = fmaxf(acc[i][3] * s[3] + off[3], 0.0f);
        *(float4*)&y[(((size_t)b * TT + t) * NN + n0 + row0 + i) * FF + f0] = v;
    }
}

// ---------------- fused GRU, all 12 steps in one kernel ----------------
__global__ __launch_bounds__(256) void gru_all(
    const float* __restrict__ y,    const float* __restrict__ wff,
    const float* __restrict__ bff,  const float* __restrict__ wzff,
    const float* __restrict__ bzff, float* __restrict__ out)
{
    __shared__ float Xs[64][36];
    __shared__ float Hs[64][36];
    __shared__ float Rs[64][36];
    __shared__ float Us[64][36];
    __shared__ float Ws[64][132];
    const int tid = threadIdx.x;
    const int mb  = blockIdx.x;
    const int b = mb >> 5, n0 = (mb & 31) * 32;
    const int rg = tid >> 5;
    const int og = tid & 31;

    for (int i = tid; i < 64 * 36; i += 256) (&Hs[0][0])[i] = 0.0f;

    for (int t = 0; t < TT; ++t) {
        {
            const float* xt = y + (((size_t)b * TT + t) * NN + n0) * DD;
            const int m = tid >> 3, c0 = (tid & 7) * 8;
            const float4 v0 = *(const float4*)&xt[m * DD + c0];
            const float4 v1 = *(const float4*)&xt[m * DD + c0 + 4];
            Xs[c0 + 0][m] = v0.x; Xs[c0 + 1][m] = v0.y;
            Xs[c0 + 2][m] = v0.z; Xs[c0 + 3][m] = v0.w;
            Xs[c0 + 4][m] = v1.x; Xs[c0 + 5][m] = v1.y;
            Xs[c0 + 6][m] = v1.z; Xs[c0 + 7][m] = v1.w;
        }
        float acc[4][4];
#pragma unroll
        for (int i = 0; i < 4; ++i)
#pragma unroll
            for (int j = 0; j < 4; ++j) acc[i][j] = 0.0f;

#pragma unroll
        for (int half = 0; half < 2; ++half) {
            __syncthreads();
#pragma unroll
            for (int p = 0; p < 8; ++p) {
                const int kk = (tid >> 5) + p * 8;
                const int o4 = (tid & 31) * 4;
                *(float4*)&Ws[kk][o4] =
                    *(const float4*)&wff[((size_t)t * 128 + half * 64 + kk) * 128 + o4];
            }
            __syncthreads();
            const float (*Asrc)[36] = half ? Hs : Xs;
#pragma unroll 4
            for (int kk = 0; kk < 64; ++kk) {
                const float4 av = *(const float4*)&Asrc[kk][rg * 4];
                const float4 wv = *(const float4*)&Ws[kk][og * 4];
                const float a0 = av.x, a1 = av.y, a2 = av.z, a3 = av.w;
                acc[0][0] = fmaf(a0, wv.x, acc[0][0]); acc[0][1] = fmaf(a0, wv.y, acc[0][1]);
                acc[0][2] = fmaf(a0, wv.z, acc[0][2]); acc[0][3] = fmaf(a0, wv.w, acc[0][3]);
                acc[1][0] = fmaf(a1, wv.x, acc[1][0]); acc[1][1] = fmaf(a1, wv.y, acc[1][1]);
                acc[1][2] = fmaf(a1, wv.z, acc[1][2]); acc[1][3] = fmaf(a1, wv.w, acc[1][3]);
                acc[2][0] = fmaf(a2, wv.x, acc[2][0]); acc[2][1] = fmaf(a2, wv.y, acc[2][1]);
                acc[2][2] = fmaf(a2, wv.z, acc[2][2]); acc[2][3] = fmaf(a2, wv.w, acc[2][3]);
                acc[3][0] = fmaf(a3, wv.x, acc[3][0]); acc[3][1] = fmaf(a3, wv.y, acc[3][1]);
                acc[3][2] = fmaf(a3, wv.z, acc[3][2]); acc[3][3] = fmaf(a3, wv.w, acc[3][3]);
            }
        }
        {
            const float4 bb4 = *(const float4*)&bff[(size_t)t * 128 + og * 4];
            float g[4][4];
#pragma unroll
            for (int i = 0; i < 4; ++i) {
                g[i][0] = sigmoidf_(acc[i][0] + bb4.x);
                g[i][1] = sigmoidf_(acc[i][1] + bb4.y);
                g[i][2] = sigmoidf_(acc[i][2] + bb4.z);
                g[i][3] = sigmoidf_(acc[i][3] + bb4.w);
            }
            if (og < 16) {
#pragma unroll
                for (int i = 0; i < 4; ++i)
#pragma unroll
                    for (int j = 0; j < 4; ++j) {
                        const int f = og * 4 + j, m = rg * 4 + i;
                        Rs[f][m] = g[i][j] * Hs[f][m];
                    }
            } else {
#pragma unroll
                for (int i = 0; i < 4; ++i)
#pragma unroll
                    for (int j = 0; j < 4; ++j)
                        Us[og * 4 + j - 64][rg * 4 + i] = g[i][j];
            }
        }
        float accz[4][2];
#pragma unroll
        for (int i = 0; i < 4; ++i) { accz[i][0] = 0.0f; accz[i][1] = 0.0f; }

#pragma unroll
        for (int half = 0; half < 2; ++half) {
            __syncthreads();
#pragma unroll
            for (int p = 0; p < 4; ++p) {
                const int kk = (tid >> 4) + p * 16;
                const int f4 = (tid & 15) * 4;
                *(float4*)&Ws[kk][f4] =
                    *(const float4*)&wzff[((size_t)t * 128 + half * 64 + kk) * 64 + f4];
            }
            __syncthreads();
            const float (*Asrc)[36] = half ? Rs : Xs;
#pragma unroll 4
            for (int kk = 0; kk < 64; ++kk) {
                const float4 av = *(const float4*)&Asrc[kk][rg * 4];
                const float2 wv = *(const float2*)&Ws[kk][og * 2];
                accz[0][0] = fmaf(av.x, wv.x, accz[0][0]); accz[0][1] = fmaf(av.x, wv.y, accz[0][1]);
                accz[1][0] = fmaf(av.y, wv.x, accz[1][0]); accz[1][1] = fmaf(av.y, wv.y, accz[1][1]);
                accz[2][0] = fmaf(av.z, wv.x, accz[2][0]); accz[2][1] = fmaf(av.z, wv.y, accz[2][1]);
                accz[3][0] = fmaf(av.w, wv.x, accz[3][0]); accz[3][1] = fmaf(av.w, wv.y, accz[3][1]);
            }
        }
        {
            const float2 bz = *(const float2*)&bzff[(size_t)t * 64 + og * 2];
            const int f0_ = og * 2;
#pragma unroll
            for (int i = 0; i < 4; ++i) {
                const int m = rg * 4 + i;
                const float z0 = tanhf(accz[i][0] + bz.x);
                const float z1 = tanhf(accz[i][1] + bz.y);
                const float u0 = Us[f0_][m],     u1 = Us[f0_ + 1][m];
                const float h0 = Hs[f0_][m],     h1 = Hs[f0_ + 1][m];
                const float hn0 = u0 * z0 + (1.0f - u0) * h0;
                const float hn1 = u1 * z1 + (1.0f - u1) * h1;
                Hs[f0_][m] = hn0; Hs[f0_ + 1][m] = hn1;
                *(float2*)&out[(((size_t)b * TT + t) * NN + n0 + m) * FF + f0_] =
                    make_float2(hn0, hn1);
            }
        }
        __syncthreads();
    }
}

extern "C" void kernel_launch(void* const* d_in, const int* in_sizes, int n_in,
                              void* d_out, int out_size, void* d_ws, size_t ws_size,
                              hipStream_t stream)
{
    const float* x        = (const float*)d_in[0];
    const float* A        = (const float*)d_in[1];
    const float* conv_w   = (const float*)d_in[2];
    const float* conv_b   = (const float*)d_in[3];
    const float* bn_gamma = (const float*)d_in[4];
    const float* bn_beta  = (const float*)d_in[5];
    const float* bn_mean  = (const float*)d_in[6];
    const float* bn_var   = (const float*)d_in[7];
    const float* gru_ff_w  = (const float*)d_in[8];
    const float* gru_ff_b  = (const float*)d_in[9];
    const float* gru_zff_w = (const float*)d_in[10];
    const float* gru_zff_b = (const float*)d_in[11];
    float* out = (float*)d_out;
    char* w = (char*)d_ws;

    const size_t szA_bf  = (size_t)NB * NN * NN * 2;    // 33,554,432 B
    const size_t szXT_bf = (size_t)NB * JT * NN * 2;    // 25,165,824 B
    const size_t needFast = 2 * szA_bf + 2 * szXT_bf + 2 * szXT_bf; // 167,772,160

    dim3 gconv(8, TT, NB);

    if (ws_size >= needFast) {
        unsigned short* Ah2 = (unsigned short*)(w);
        unsigned short* Al2 = (unsigned short*)(w + szA_bf);
        unsigned short* X1h = (unsigned short*)(w + 2 * szA_bf);
        unsigned short* X1l = (unsigned short*)(w + 2 * szA_bf + szXT_bf);
        char* slot = w + 2 * szA_bf + 2 * szXT_bf;      // 50.33 MB
        unsigned short* xh = (unsigned short*)slot;
        unsigned short* xl = (unsigned short*)(slot + szXT_bf);
        float* X2T = (float*)slot;                       // after xh/xl dead
        float* yb  = (float*)w;                          // over Ah/Al after gemm2

        xsplitT<<<dim3(16, TT, NB), 256, 0, stream>>>(x, xh, xl);
        split_A<<<4096, 256, 0, stream>>>(A, Ah2, Al2);
        gemm_bf<true ><<<768, 256, 0, stream>>>(Ah2, Al2, xh,  xl,  X1h, X1l, nullptr);
        gemm_bf<false><<<768, 256, 0, stream>>>(Ah2, Al2, X1h, X1l, nullptr, nullptr, X2T);
        conv_bn_relu<true><<<gconv, 256, 0, stream>>>(x, X1h, X1l, X2T, nullptr, nullptr,
                                                      conv_w, conv_b, bn_gamma, bn_beta,
                                                      bn_mean, bn_var, yb);
        gru_all<<<512, 256, 0, stream>>>(yb, gru_ff_w, gru_ff_b,
                                         gru_zff_w, gru_zff_b, out);
    } else {
        const size_t szX = (size_t)NB * NN * JT;        // floats
        float* X1 = (float*)w;
        float* X2 = X1 + szX;
        float* yb = X2 + szX;
        gemm_f32<true ><<<768, 256, 0, stream>>>(A, x,  X1);
        gemm_f32<false><<<768, 256, 0, stream>>>(A, X1, X2);
        conv_bn_relu<false><<<gconv, 256, 0, stream>>>(x, nullptr, nullptr, nullptr, X1, X2,
                                                       conv_w, conv_b, bn_gamma, bn_beta,
                                                       bn_mean, bn_var, yb);
        gru_all<<<512, 256, 0, stream>>>(yb, gru_ff_w, gru_ff_b,
                                         gru_zff_w, gru_zff_b, out);
    }
}